// Round 2
// baseline (797.138 us; speedup 1.0000x reference)
//
#include <hip/hip_runtime.h>
#include <hip/hip_bf16.h>

#define NN 16384      // nodes
#define EE 8192       // edges
#define DD 128        // feature dim (in == out)
#define CSR_STRIDE 128   // max node degree slot (mean 41, sd 6.4 -> 13 sigma margin)
#define CSC_STRIDE 192   // max edge degree slot (mean 82, sd 9 -> 12 sigma margin)
#define GEMM_BLOCKS 512  // NN/32 rows per gemm block

typedef float vfloat4 __attribute__((ext_vector_type(4)));

// bf16 pack/unpack (RNE). Intermediates xw/y2 stored bf16 to halve gather
// traffic and make them per-XCD-L2 resident (4 MB / 2 MB); accum stays fp32.
__device__ __forceinline__ unsigned short f2bf(float f) {
    union { float f; unsigned u; } c; c.f = f;
    unsigned u = c.u + (0x7FFFu + ((c.u >> 16) & 1u));
    return (unsigned short)(u >> 16);
}
__device__ __forceinline__ float bf2f(unsigned short h) {
    union { unsigned u; float f; } c; c.u = ((unsigned)h) << 16;
    return c.f;
}

// ---------------- workspace layout (bytes) ----------------
// dvih      : NN f32                      @ 0          (64 KB)
// csr_cnt   : NN i32                      @ 65536      (64 KB)
// edge_cnt  : EE i32                      @ 131072     (32 KB)
// csr_idx   : NN*CSR_STRIDE i32           @ 163840     (8 MB)
// csc_idx   : EE*CSC_STRIDE i32           @ 8552448    (6 MB)
// xw        : NN*DD bf16                  @ 14843904   (4 MB)
// y2        : EE*DD bf16                  @ 19038208   (2 MB)
// total ~21 MB

// R6: gemm fused into the parse kernel. gemm blocks (blockIdx < 512) run
// LDS-FREE (a-loads broadcast to 16 lanes via L1; W is 64 KB, L1/L2-resident
// across all gemm blocks), so the fused kernel's LDS footprint stays at
// parse's 516 B -> 8 blocks/CU preserved (the R3 lesson: 50 KB LDS here
// costs ~33 us). gemm's ~537 MFLOP + 12 MB traffic hides inside parse's
// BW-bound 537 MB H stream. edge_cnt zeroing moved to hipMemsetAsync.
__global__ __launch_bounds__(256) void k01_fused(
    const float* __restrict__ x,
    const float* __restrict__ W,
    const float* __restrict__ H,
    ushort4* __restrict__ xwb,          // [NN][32] ushort4 rows
    float* __restrict__ dvih,
    int* __restrict__ csr_cnt,
    int* __restrict__ csr_idx,
    int* __restrict__ edge_cnt,
    int* __restrict__ csc_idx)
{
    const int t = threadIdx.x;
    __shared__ int s_cnt;
    __shared__ int s_list[CSR_STRIDE];

    if (blockIdx.x < GEMM_BLOCKS) {
        // ---- gemm branch: xw = bf16(x @ W^T), 32 rows per block ----
        const int m0 = blockIdx.x * 32;
        const int jg = t & 15;    // j-group -> 4 consecutive j
        const int mg = t >> 4;    // 0..15   -> 2 consecutive m
        const int m2 = mg * 2;
        const int j4 = jg * 4;
        const float* a0p = x + (size_t)(m0 + m2) * DD;
        const float* a1p = a0p + DD;

        for (int h = 0; h < 2; ++h) {
            const float* wb = W + (size_t)(h * 64 + j4) * DD;
            float acc0[4] = {0.f, 0.f, 0.f, 0.f};
            float acc1[4] = {0.f, 0.f, 0.f, 0.f};
#pragma unroll 4
            for (int k = 0; k < 128; k += 4) {
                float4 a0 = *(const float4*)&a0p[k];
                float4 a1 = *(const float4*)&a1p[k];
#pragma unroll
                for (int jj = 0; jj < 4; ++jj) {
                    float4 w = *(const float4*)&wb[jj * DD + k];
                    acc0[jj] += a0.x*w.x + a0.y*w.y + a0.z*w.z + a0.w*w.w;
                    acc1[jj] += a1.x*w.x + a1.y*w.y + a1.z*w.z + a1.w*w.w;
                }
            }
            ushort4 p0, p1;
            p0.x = f2bf(acc0[0]); p0.y = f2bf(acc0[1]); p0.z = f2bf(acc0[2]); p0.w = f2bf(acc0[3]);
            p1.x = f2bf(acc1[0]); p1.y = f2bf(acc1[1]); p1.z = f2bf(acc1[2]); p1.w = f2bf(acc1[3]);
            xwb[(size_t)(m0 + m2)     * 32 + h * 16 + jg] = p0;
            xwb[(size_t)(m0 + m2 + 1) * 32 + h * 16 + jg] = p1;
        }
        return;
    }

    // ---- parse branch: one node row (32 KB contiguous H stream) ----
    const int n = blockIdx.x - GEMM_BLOCKS;
    if (t == 0) s_cnt = 0;
    __syncthreads();

    const vfloat4* row = (const vfloat4*)(H + (size_t)n * EE);
#pragma unroll
    for (int j = 0; j < 8; ++j) {
        int idx = t + 256 * j;          // float4 index in row (0..2047)
        vfloat4 v = __builtin_nontemporal_load(row + idx);
        int base = idx * 4;
        if (v[0] != 0.0f) { int p = atomicAdd(&s_cnt, 1); if (p < CSR_STRIDE) s_list[p] = base + 0; }
        if (v[1] != 0.0f) { int p = atomicAdd(&s_cnt, 1); if (p < CSR_STRIDE) s_list[p] = base + 1; }
        if (v[2] != 0.0f) { int p = atomicAdd(&s_cnt, 1); if (p < CSR_STRIDE) s_list[p] = base + 2; }
        if (v[3] != 0.0f) { int p = atomicAdd(&s_cnt, 1); if (p < CSR_STRIDE) s_list[p] = base + 3; }
    }
    __syncthreads();

    int cnt = s_cnt; if (cnt > CSR_STRIDE) cnt = CSR_STRIDE;
    if (t < cnt) {
        int e = s_list[t];
        csr_idx[(size_t)n * CSR_STRIDE + t] = e;
        int pos = atomicAdd(&edge_cnt[e], 1);       // device-scope, builds CSC
        if (pos < CSC_STRIDE) csc_idx[(size_t)e * CSC_STRIDE + pos] = n;
    }
    if (t == 0) {
        csr_cnt[n] = cnt;
        dvih[n] = (cnt > 0) ? (1.0f / sqrtf((float)cnt)) : 0.0f;
    }
}

// K2: per edge e: y2[e,:] = bf16( dei[e] * sum_{n in col(e)} dvih[n]*xw[n,:] )
// One WAVE per edge (4 edges / 256-thread block). Two 32-lane groups
// interleave over the node list (unroll 8 -> 8 loads in flight), final
// cross-half reduce is a single shfl_xor(32).
// R6: nontemporal staging loads (csc_idx read-once; keep xwb cached).
__global__ __launch_bounds__(256) void k2_edge_gather(
    const ushort4* __restrict__ xwb,
    const float* __restrict__ dvih,
    const int* __restrict__ edge_cnt,
    const int* __restrict__ csc_idx,
    ushort4* __restrict__ y2b)
{
    const int t    = threadIdx.x;
    const int w    = t >> 6;        // wave in block -> edge slot
    const int lane = t & 63;
    const int grp  = lane >> 5;     // 0..1 half-wave
    const int fl   = lane & 31;     // ushort4 column (4 features)
    const int e    = blockIdx.x * 4 + w;

    __shared__ int    s_lst[4][CSC_STRIDE];
    __shared__ float  s_dv[4][CSC_STRIDE];

    int cnt = edge_cnt[e];
    int ccnt = cnt > CSC_STRIDE ? CSC_STRIDE : cnt;
    for (int i = lane; i < ccnt; i += 64) {
        int n = __builtin_nontemporal_load(&csc_idx[(size_t)e * CSC_STRIDE + i]);
        s_lst[w][i] = n;
        s_dv[w][i]  = dvih[n];
    }
    __syncthreads();

    float ax = 0.f, ay = 0.f, az = 0.f, aw = 0.f;
    int i = grp;
    for (; i + 14 < ccnt; i += 16) {
        ushort4 v0 = xwb[(size_t)s_lst[w][i     ] * 32 + fl];
        ushort4 v1 = xwb[(size_t)s_lst[w][i +  2] * 32 + fl];
        ushort4 v2 = xwb[(size_t)s_lst[w][i +  4] * 32 + fl];
        ushort4 v3 = xwb[(size_t)s_lst[w][i +  6] * 32 + fl];
        ushort4 v4 = xwb[(size_t)s_lst[w][i +  8] * 32 + fl];
        ushort4 v5 = xwb[(size_t)s_lst[w][i + 10] * 32 + fl];
        ushort4 v6 = xwb[(size_t)s_lst[w][i + 12] * 32 + fl];
        ushort4 v7 = xwb[(size_t)s_lst[w][i + 14] * 32 + fl];
        float f0 = s_dv[w][i],      f1 = s_dv[w][i +  2];
        float f2 = s_dv[w][i +  4], f3 = s_dv[w][i +  6];
        float f4 = s_dv[w][i +  8], f5 = s_dv[w][i + 10];
        float f6 = s_dv[w][i + 12], f7 = s_dv[w][i + 14];
        ax += f0*bf2f(v0.x) + f1*bf2f(v1.x) + f2*bf2f(v2.x) + f3*bf2f(v3.x)
            + f4*bf2f(v4.x) + f5*bf2f(v5.x) + f6*bf2f(v6.x) + f7*bf2f(v7.x);
        ay += f0*bf2f(v0.y) + f1*bf2f(v1.y) + f2*bf2f(v2.y) + f3*bf2f(v3.y)
            + f4*bf2f(v4.y) + f5*bf2f(v5.y) + f6*bf2f(v6.y) + f7*bf2f(v7.y);
        az += f0*bf2f(v0.z) + f1*bf2f(v1.z) + f2*bf2f(v2.z) + f3*bf2f(v3.z)
            + f4*bf2f(v4.z) + f5*bf2f(v5.z) + f6*bf2f(v6.z) + f7*bf2f(v7.z);
        aw += f0*bf2f(v0.w) + f1*bf2f(v1.w) + f2*bf2f(v2.w) + f3*bf2f(v3.w)
            + f4*bf2f(v4.w) + f5*bf2f(v5.w) + f6*bf2f(v6.w) + f7*bf2f(v7.w);
    }
    for (; i < ccnt; i += 2) {
        ushort4 v = xwb[(size_t)s_lst[w][i] * 32 + fl];
        float f = s_dv[w][i];
        ax += f*bf2f(v.x); ay += f*bf2f(v.y); az += f*bf2f(v.z); aw += f*bf2f(v.w);
    }

    ax += __shfl_xor(ax, 32);
    ay += __shfl_xor(ay, 32);
    az += __shfl_xor(az, 32);
    aw += __shfl_xor(aw, 32);

    if (grp == 0) {
        float dei = (cnt > 0) ? (1.0f / (float)cnt) : 0.0f;
        ushort4 o;
        o.x = f2bf(ax * dei);
        o.y = f2bf(ay * dei);
        o.z = f2bf(az * dei);
        o.w = f2bf(aw * dei);
        y2b[(size_t)e * 32 + fl] = o;
    }
}

// K3: per node n: out[n,:] = dvih[n] * sum_{e in row(n)} y2[e,:] + b[:]
// One wave per node, same structure as K2 (unroll 4: avg ~20 iters/group).
__global__ __launch_bounds__(256) void k3_node_gather(
    const ushort4* __restrict__ y2b,
    const float* __restrict__ dvih,
    const int* __restrict__ csr_cnt,
    const int* __restrict__ csr_idx,
    const float* __restrict__ b,
    float* __restrict__ out)
{
    const int t    = threadIdx.x;
    const int w    = t >> 6;        // wave in block -> node slot
    const int lane = t & 63;
    const int grp  = lane >> 5;
    const int fl   = lane & 31;     // 4 consecutive features
    const int n    = blockIdx.x * 4 + w;

    __shared__ int s_lst[4][CSR_STRIDE];

    int cnt = csr_cnt[n];
    for (int i = lane; i < cnt; i += 64)
        s_lst[w][i] = __builtin_nontemporal_load(&csr_idx[(size_t)n * CSR_STRIDE + i]);
    __syncthreads();

    float ax = 0.f, ay = 0.f, az = 0.f, aw = 0.f;
    int i = grp;
    for (; i + 6 < cnt; i += 8) {
        ushort4 v0 = y2b[(size_t)s_lst[w][i    ] * 32 + fl];
        ushort4 v1 = y2b[(size_t)s_lst[w][i + 2] * 32 + fl];
        ushort4 v2 = y2b[(size_t)s_lst[w][i + 4] * 32 + fl];
        ushort4 v3 = y2b[(size_t)s_lst[w][i + 6] * 32 + fl];
        ax += bf2f(v0.x) + bf2f(v1.x) + bf2f(v2.x) + bf2f(v3.x);
        ay += bf2f(v0.y) + bf2f(v1.y) + bf2f(v2.y) + bf2f(v3.y);
        az += bf2f(v0.z) + bf2f(v1.z) + bf2f(v2.z) + bf2f(v3.z);
        aw += bf2f(v0.w) + bf2f(v1.w) + bf2f(v2.w) + bf2f(v3.w);
    }
    for (; i < cnt; i += 2) {
        ushort4 v = y2b[(size_t)s_lst[w][i] * 32 + fl];
        ax += bf2f(v.x); ay += bf2f(v.y); az += bf2f(v.z); aw += bf2f(v.w);
    }

    ax += __shfl_xor(ax, 32);
    ay += __shfl_xor(ay, 32);
    az += __shfl_xor(az, 32);
    aw += __shfl_xor(aw, 32);

    if (grp == 0) {
        float dv = dvih[n];
        float4 bb = ((const float4*)b)[fl];
        float4 o = make_float4(ax * dv + bb.x,
                               ay * dv + bb.y,
                               az * dv + bb.z,
                               aw * dv + bb.w);
        ((float4*)out)[(size_t)n * 32 + fl] = o;
    }
}

extern "C" void kernel_launch(void* const* d_in, const int* in_sizes, int n_in,
                              void* d_out, int out_size, void* d_ws, size_t ws_size,
                              hipStream_t stream) {
    const float* x = (const float*)d_in[0];   // [16384,128]
    const float* H = (const float*)d_in[1];   // [16384,8192]
    const float* W = (const float*)d_in[2];   // [128,128]
    const float* b = (const float*)d_in[3];   // [128]
    float* out = (float*)d_out;

    char* ws = (char*)d_ws;
    float*   dvih    = (float*)  (ws + 0);
    int*     csr_cnt = (int*)    (ws + 65536);
    int*     edge_cnt= (int*)    (ws + 131072);
    int*     csr_idx = (int*)    (ws + 163840);
    int*     csc_idx = (int*)    (ws + 8552448);
    ushort4* xwb     = (ushort4*)(ws + 14843904);
    ushort4* y2b     = (ushort4*)(ws + 19038208);

    hipMemsetAsync(edge_cnt, 0, EE * sizeof(int), stream);
    k01_fused<<<GEMM_BLOCKS + NN, 256, 0, stream>>>(
        x, W, H, xwb, dvih, csr_cnt, csr_idx, edge_cnt, csc_idx);
    k2_edge_gather<<<EE / 4, 256, 0, stream>>>(xwb, dvih, edge_cnt, csc_idx, y2b);
    k3_node_gather<<<NN / 4, 256, 0, stream>>>(y2b, dvih, csr_cnt, csr_idx, b, out);
}

// Round 3
// 727.602 us; speedup vs baseline: 1.0956x; 1.0956x over previous
//
#include <hip/hip_runtime.h>
#include <hip/hip_bf16.h>

#define NN 16384      // nodes
#define EE 8192       // edges
#define DD 128        // feature dim (in == out)
#define CSR_STRIDE 128   // max node degree slot (mean 41, sd 6.4 -> 13 sigma margin)
#define CSC_STRIDE 192   // max edge degree slot (mean 82, sd 9 -> 12 sigma margin)

typedef float vfloat4 __attribute__((ext_vector_type(4)));

// bf16 pack/unpack (RNE). Intermediates xw/y2 stored bf16 to halve gather
// traffic and make them per-XCD-L2 resident (4 MB / 2 MB); accum stays fp32.
__device__ __forceinline__ unsigned short f2bf(float f) {
    union { float f; unsigned u; } c; c.f = f;
    unsigned u = c.u + (0x7FFFu + ((c.u >> 16) & 1u));
    return (unsigned short)(u >> 16);
}
// unpack the two bf16 packed in one uint (low = even feature, high = odd)
__device__ __forceinline__ float bflo(unsigned u) {
    union { unsigned u; float f; } c; c.u = u << 16; return c.f;
}
__device__ __forceinline__ float bfhi(unsigned u) {
    union { unsigned u; float f; } c; c.u = u & 0xffff0000u; return c.f;
}
__device__ __forceinline__ unsigned packbf(float lo, float hi) {
    return (unsigned)f2bf(lo) | ((unsigned)f2bf(hi) << 16);
}

// ---------------- workspace layout (bytes) ----------------
// dvih      : NN f32                      @ 0          (64 KB)
// csr_cnt   : NN i32                      @ 65536      (64 KB)
// edge_cnt  : EE i32                      @ 131072     (32 KB)
// csr_idx   : NN*CSR_STRIDE i32           @ 163840     (8 MB)
// csc_idx   : EE*CSC_STRIDE i32           @ 8552448    (6 MB)
// xw        : NN*DD bf16                  @ 14843904   (4 MB)
// y2        : EE*DD bf16                  @ 19038208   (2 MB)
// total ~21 MB

// G: xw = bf16(x @ W^T)  (M=16384, N=128, K=128, fp32 LDS-tiled). Also zeroes
// the edge cursors (runs before k1_parse in stream order).
// R7 note: R2's LDS-free fused variant regressed +67us — the LDS tile is a
// VMEM-instruction-count reducer, not just a cache. Keep it separate+tiled.
__global__ __launch_bounds__(256) void g_gemm(
    const float* __restrict__ x,
    const float* __restrict__ W,
    ushort4* __restrict__ xwb,          // [NN][32] ushort4 rows
    int* __restrict__ edge_cnt)
{
    const int t = threadIdx.x;
    {
        int tid = blockIdx.x * 256 + t;
        if (tid < EE) edge_cnt[tid] = 0;
    }

    __shared__ float sA[32 * 132];
    __shared__ float sW[64 * 132];
    const int m0 = blockIdx.x * 32;

    // stage A tile: 32 rows x 128 cols = 1024 float4, 4 per thread
#pragma unroll
    for (int r = 0; r < 4; ++r) {
        int i = t + 256 * r;            // float4 index 0..1023
        int row = i >> 5, c4 = (i & 31) << 2;
        *(float4*)&sA[row * 132 + c4] =
            *(const float4*)&x[(size_t)(m0 + row) * DD + c4];
    }

    const int jg = t & 15;    // j-group -> 4 consecutive j
    const int mg = t >> 4;    // 0..15   -> 2 consecutive m
    const int m2 = mg * 2;
    const int j4 = jg * 4;

    for (int h = 0; h < 2; ++h) {
        __syncthreads();
        // stage W half: 64 rows x 128 cols = 2048 float4, 8 per thread
#pragma unroll
        for (int r = 0; r < 8; ++r) {
            int i = t + 256 * r;        // float4 index 0..2047
            int row = i >> 5, c4 = (i & 31) << 2;
            *(float4*)&sW[row * 132 + c4] =
                *(const float4*)&W[(size_t)(h * 64 + row) * DD + c4];
        }
        __syncthreads();

        float acc0[4] = {0.f, 0.f, 0.f, 0.f};
        float acc1[4] = {0.f, 0.f, 0.f, 0.f};
#pragma unroll 4
        for (int k = 0; k < 128; k += 4) {
            float4 a0 = *(const float4*)&sA[m2 * 132 + k];
            float4 a1 = *(const float4*)&sA[(m2 + 1) * 132 + k];
#pragma unroll
            for (int jj = 0; jj < 4; ++jj) {
                float4 w = *(const float4*)&sW[(j4 + jj) * 132 + k];
                acc0[jj] += a0.x*w.x + a0.y*w.y + a0.z*w.z + a0.w*w.w;
                acc1[jj] += a1.x*w.x + a1.y*w.y + a1.z*w.z + a1.w*w.w;
            }
        }
        ushort4 p0, p1;
        p0.x = f2bf(acc0[0]); p0.y = f2bf(acc0[1]); p0.z = f2bf(acc0[2]); p0.w = f2bf(acc0[3]);
        p1.x = f2bf(acc1[0]); p1.y = f2bf(acc1[1]); p1.z = f2bf(acc1[2]); p1.w = f2bf(acc1[3]);
        xwb[(size_t)(m0 + m2)     * 32 + h * 16 + jg] = p0;
        xwb[(size_t)(m0 + m2 + 1) * 32 + h * 16 + jg] = p1;
    }
}

// K1: one full pass over H. Per block = one node row (32 KB contiguous).
// Small LDS footprint -> 8 blocks/CU, 32 waves: saturates HBM. Nontemporal H
// loads: read-once stream must not evict xwb (4 MB) from L2.
__global__ __launch_bounds__(256) void k1_parse(
    const float* __restrict__ H,
    float* __restrict__ dvih,
    int* __restrict__ csr_cnt,
    int* __restrict__ csr_idx,
    int* __restrict__ edge_cnt,
    int* __restrict__ csc_idx)
{
    const int n = blockIdx.x;
    const int t = threadIdx.x;
    __shared__ int s_cnt;
    __shared__ int s_list[CSR_STRIDE];
    if (t == 0) s_cnt = 0;
    __syncthreads();

    const vfloat4* row = (const vfloat4*)(H + (size_t)n * EE);
#pragma unroll
    for (int j = 0; j < 8; ++j) {
        int idx = t + 256 * j;          // float4 index in row (0..2047)
        vfloat4 v = __builtin_nontemporal_load(row + idx);
        int base = idx * 4;
        if (v[0] != 0.0f) { int p = atomicAdd(&s_cnt, 1); if (p < CSR_STRIDE) s_list[p] = base + 0; }
        if (v[1] != 0.0f) { int p = atomicAdd(&s_cnt, 1); if (p < CSR_STRIDE) s_list[p] = base + 1; }
        if (v[2] != 0.0f) { int p = atomicAdd(&s_cnt, 1); if (p < CSR_STRIDE) s_list[p] = base + 2; }
        if (v[3] != 0.0f) { int p = atomicAdd(&s_cnt, 1); if (p < CSR_STRIDE) s_list[p] = base + 3; }
    }
    __syncthreads();

    int cnt = s_cnt; if (cnt > CSR_STRIDE) cnt = CSR_STRIDE;
    if (t < cnt) {
        int e = s_list[t];
        csr_idx[(size_t)n * CSR_STRIDE + t] = e;
        int pos = atomicAdd(&edge_cnt[e], 1);       // device-scope, builds CSC
        if (pos < CSC_STRIDE) csc_idx[(size_t)e * CSC_STRIDE + pos] = n;
    }
    if (t == 0) {
        csr_cnt[n] = cnt;
        dvih[n] = (cnt > 0) ? (1.0f / sqrtf((float)cnt)) : 0.0f;
    }
}

// K2: per edge e: y2[e,:] = bf16( dei[e] * sum_{n in col(e)} dvih[n]*xw[n,:] )
// One WAVE per edge (4 edges / 256-thread block). R7: 16B uint4 gather loads
// (8 bf16 features per lane, 16 lanes/row, 4 interleave groups) — half the
// VMEM instructions of the ushort4 version, same bytes in flight. Unpack is
// 1 shift + 1 and per bf16 pair. Cross-group reduce: shfl_xor 16 + 32.
__global__ __launch_bounds__(256) void k2_edge_gather(
    const uint4* __restrict__ xwb,      // [NN][16] uint4 rows
    const float* __restrict__ dvih,
    const int* __restrict__ edge_cnt,
    const int* __restrict__ csc_idx,
    uint4* __restrict__ y2b)            // [EE][16] uint4 rows
{
    const int t    = threadIdx.x;
    const int w    = t >> 6;        // wave in block -> edge slot
    const int lane = t & 63;
    const int grp  = lane >> 4;     // 0..3 quarter-wave
    const int fl   = lane & 15;     // uint4 column (8 features)
    const int e    = blockIdx.x * 4 + w;

    __shared__ int    s_lst[4][CSC_STRIDE];
    __shared__ float  s_dv[4][CSC_STRIDE];

    int cnt = edge_cnt[e];
    int ccnt = cnt > CSC_STRIDE ? CSC_STRIDE : cnt;
    for (int i = lane; i < ccnt; i += 64) {
        int n = __builtin_nontemporal_load(&csc_idx[(size_t)e * CSC_STRIDE + i]);
        s_lst[w][i] = n;
        s_dv[w][i]  = dvih[n];
    }
    __syncthreads();

    float a0=0.f,a1=0.f,a2=0.f,a3=0.f,a4=0.f,a5=0.f,a6=0.f,a7=0.f;
    int i = grp;
    for (; i + 12 < ccnt; i += 16) {
        uint4 v0 = xwb[(size_t)s_lst[w][i     ] * 16 + fl];
        uint4 v1 = xwb[(size_t)s_lst[w][i +  4] * 16 + fl];
        uint4 v2 = xwb[(size_t)s_lst[w][i +  8] * 16 + fl];
        uint4 v3 = xwb[(size_t)s_lst[w][i + 12] * 16 + fl];
        float f0 = s_dv[w][i],     f1 = s_dv[w][i + 4];
        float f2 = s_dv[w][i + 8], f3 = s_dv[w][i + 12];
        a0 += f0*bflo(v0.x) + f1*bflo(v1.x) + f2*bflo(v2.x) + f3*bflo(v3.x);
        a1 += f0*bfhi(v0.x) + f1*bfhi(v1.x) + f2*bfhi(v2.x) + f3*bfhi(v3.x);
        a2 += f0*bflo(v0.y) + f1*bflo(v1.y) + f2*bflo(v2.y) + f3*bflo(v3.y);
        a3 += f0*bfhi(v0.y) + f1*bfhi(v1.y) + f2*bfhi(v2.y) + f3*bfhi(v3.y);
        a4 += f0*bflo(v0.z) + f1*bflo(v1.z) + f2*bflo(v2.z) + f3*bflo(v3.z);
        a5 += f0*bfhi(v0.z) + f1*bfhi(v1.z) + f2*bfhi(v2.z) + f3*bfhi(v3.z);
        a6 += f0*bflo(v0.w) + f1*bflo(v1.w) + f2*bflo(v2.w) + f3*bflo(v3.w);
        a7 += f0*bfhi(v0.w) + f1*bfhi(v1.w) + f2*bfhi(v2.w) + f3*bfhi(v3.w);
    }
    for (; i < ccnt; i += 4) {
        uint4 v = xwb[(size_t)s_lst[w][i] * 16 + fl];
        float f = s_dv[w][i];
        a0 += f*bflo(v.x); a1 += f*bfhi(v.x);
        a2 += f*bflo(v.y); a3 += f*bfhi(v.y);
        a4 += f*bflo(v.z); a5 += f*bfhi(v.z);
        a6 += f*bflo(v.w); a7 += f*bfhi(v.w);
    }

    a0 += __shfl_xor(a0, 16); a0 += __shfl_xor(a0, 32);
    a1 += __shfl_xor(a1, 16); a1 += __shfl_xor(a1, 32);
    a2 += __shfl_xor(a2, 16); a2 += __shfl_xor(a2, 32);
    a3 += __shfl_xor(a3, 16); a3 += __shfl_xor(a3, 32);
    a4 += __shfl_xor(a4, 16); a4 += __shfl_xor(a4, 32);
    a5 += __shfl_xor(a5, 16); a5 += __shfl_xor(a5, 32);
    a6 += __shfl_xor(a6, 16); a6 += __shfl_xor(a6, 32);
    a7 += __shfl_xor(a7, 16); a7 += __shfl_xor(a7, 32);

    if (grp == 0) {
        float dei = (cnt > 0) ? (1.0f / (float)cnt) : 0.0f;
        uint4 o;
        o.x = packbf(a0 * dei, a1 * dei);
        o.y = packbf(a2 * dei, a3 * dei);
        o.z = packbf(a4 * dei, a5 * dei);
        o.w = packbf(a6 * dei, a7 * dei);
        y2b[(size_t)e * 16 + fl] = o;
    }
}

// K3: per node n: out[n,:] = dvih[n] * sum_{e in row(n)} y2[e,:] + b[:]
// One wave per node; same 16B-load structure as K2 (unroll 2: avg ~10
// iters/group at mean degree 41). fp32 output, 32B per grp-0 lane.
__global__ __launch_bounds__(256) void k3_node_gather(
    const uint4* __restrict__ y2b,
    const float* __restrict__ dvih,
    const int* __restrict__ csr_cnt,
    const int* __restrict__ csr_idx,
    const float* __restrict__ b,
    float* __restrict__ out)
{
    const int t    = threadIdx.x;
    const int w    = t >> 6;        // wave in block -> node slot
    const int lane = t & 63;
    const int grp  = lane >> 4;     // 0..3
    const int fl   = lane & 15;     // uint4 column (8 features)
    const int n    = blockIdx.x * 4 + w;

    __shared__ int s_lst[4][CSR_STRIDE];

    int cnt = csr_cnt[n];
    for (int i = lane; i < cnt; i += 64)
        s_lst[w][i] = __builtin_nontemporal_load(&csr_idx[(size_t)n * CSR_STRIDE + i]);
    __syncthreads();

    float a0=0.f,a1=0.f,a2=0.f,a3=0.f,a4=0.f,a5=0.f,a6=0.f,a7=0.f;
    int i = grp;
    for (; i + 4 < cnt; i += 8) {
        uint4 v0 = y2b[(size_t)s_lst[w][i    ] * 16 + fl];
        uint4 v1 = y2b[(size_t)s_lst[w][i + 4] * 16 + fl];
        a0 += bflo(v0.x) + bflo(v1.x); a1 += bfhi(v0.x) + bfhi(v1.x);
        a2 += bflo(v0.y) + bflo(v1.y); a3 += bfhi(v0.y) + bfhi(v1.y);
        a4 += bflo(v0.z) + bflo(v1.z); a5 += bfhi(v0.z) + bfhi(v1.z);
        a6 += bflo(v0.w) + bflo(v1.w); a7 += bfhi(v0.w) + bfhi(v1.w);
    }
    for (; i < cnt; i += 4) {
        uint4 v = y2b[(size_t)s_lst[w][i] * 16 + fl];
        a0 += bflo(v.x); a1 += bfhi(v.x);
        a2 += bflo(v.y); a3 += bfhi(v.y);
        a4 += bflo(v.z); a5 += bfhi(v.z);
        a6 += bflo(v.w); a7 += bfhi(v.w);
    }

    a0 += __shfl_xor(a0, 16); a0 += __shfl_xor(a0, 32);
    a1 += __shfl_xor(a1, 16); a1 += __shfl_xor(a1, 32);
    a2 += __shfl_xor(a2, 16); a2 += __shfl_xor(a2, 32);
    a3 += __shfl_xor(a3, 16); a3 += __shfl_xor(a3, 32);
    a4 += __shfl_xor(a4, 16); a4 += __shfl_xor(a4, 32);
    a5 += __shfl_xor(a5, 16); a5 += __shfl_xor(a5, 32);
    a6 += __shfl_xor(a6, 16); a6 += __shfl_xor(a6, 32);
    a7 += __shfl_xor(a7, 16); a7 += __shfl_xor(a7, 32);

    if (grp == 0) {
        float dv = dvih[n];
        float4 bb0 = ((const float4*)b)[fl * 2];
        float4 bb1 = ((const float4*)b)[fl * 2 + 1];
        float4 o0 = make_float4(a0 * dv + bb0.x, a1 * dv + bb0.y,
                                a2 * dv + bb0.z, a3 * dv + bb0.w);
        float4 o1 = make_float4(a4 * dv + bb1.x, a5 * dv + bb1.y,
                                a6 * dv + bb1.z, a7 * dv + bb1.w);
        ((float4*)out)[(size_t)n * 32 + fl * 2]     = o0;
        ((float4*)out)[(size_t)n * 32 + fl * 2 + 1] = o1;
    }
}

extern "C" void kernel_launch(void* const* d_in, const int* in_sizes, int n_in,
                              void* d_out, int out_size, void* d_ws, size_t ws_size,
                              hipStream_t stream) {
    const float* x = (const float*)d_in[0];   // [16384,128]
    const float* H = (const float*)d_in[1];   // [16384,8192]
    const float* W = (const float*)d_in[2];   // [128,128]
    const float* b = (const float*)d_in[3];   // [128]
    float* out = (float*)d_out;

    char* ws = (char*)d_ws;
    float*   dvih    = (float*)  (ws + 0);
    int*     csr_cnt = (int*)    (ws + 65536);
    int*     edge_cnt= (int*)    (ws + 131072);
    int*     csr_idx = (int*)    (ws + 163840);
    int*     csc_idx = (int*)    (ws + 8552448);
    ushort4* xwb     = (ushort4*)(ws + 14843904);
    uint4*   y2b     = (uint4*)  (ws + 19038208);

    g_gemm<<<NN / 32, 256, 0, stream>>>(x, W, xwb, edge_cnt);
    k1_parse<<<NN, 256, 0, stream>>>(H, dvih, csr_cnt, csr_idx, edge_cnt, csc_idx);
    k2_edge_gather<<<EE / 4, 256, 0, stream>>>((const uint4*)xwb, dvih, edge_cnt, csc_idx, y2b);
    k3_node_gather<<<NN / 4, 256, 0, stream>>>(y2b, dvih, csr_cnt, csr_idx, b, out);
}